// Round 3
// baseline (203.222 us; speedup 1.0000x reference)
//
#include <hip/hip_runtime.h>

#define BLOCK 256
#define NBLOCKS 2048

// Single-pass fused reduction + finalize (last-block-done pattern).
// Cross-block communication uses agent(device)-scope atomics explicitly,
// since per-XCD L2s are not coherent (G16).
__global__ __launch_bounds__(BLOCK) void nll_fused(
    const float4* __restrict__ x4,
    const int4* __restrict__ t4,
    float* __restrict__ ps0,          // [NBLOCKS]
    float* __restrict__ ps1,          // [NBLOCKS]
    unsigned int* __restrict__ pc1,   // [NBLOCKS]
    unsigned int* __restrict__ counter,
    const float* __restrict__ x,
    const int* __restrict__ tg,
    float* __restrict__ out,
    int nquads, int N, int tail_start)
{
    int idx = blockIdx.x * blockDim.x + threadIdx.x;
    int stride = gridDim.x * blockDim.x;

    float s0 = 0.f, s1 = 0.f;
    unsigned int c1 = 0;

    for (int i = idx; i < nquads; i += stride) {
        float4 xa = x4[2 * i];
        float4 xb = x4[2 * i + 1];
        int4   t  = t4[i];

        float a, b, m, lse;

        a = xa.x; b = xa.y;
        m = fmaxf(a, b);
        lse = m + __logf(__expf(a - m) + __expf(b - m));
        s1 += t.x ? (lse - b) : 0.f;
        s0 += t.x ? 0.f : (lse - a);
        c1 += (t.x != 0);

        a = xa.z; b = xa.w;
        m = fmaxf(a, b);
        lse = m + __logf(__expf(a - m) + __expf(b - m));
        s1 += t.y ? (lse - b) : 0.f;
        s0 += t.y ? 0.f : (lse - a);
        c1 += (t.y != 0);

        a = xb.x; b = xb.y;
        m = fmaxf(a, b);
        lse = m + __logf(__expf(a - m) + __expf(b - m));
        s1 += t.z ? (lse - b) : 0.f;
        s0 += t.z ? 0.f : (lse - a);
        c1 += (t.z != 0);

        a = xb.z; b = xb.w;
        m = fmaxf(a, b);
        lse = m + __logf(__expf(a - m) + __expf(b - m));
        s1 += t.w ? (lse - b) : 0.f;
        s0 += t.w ? 0.f : (lse - a);
        c1 += (t.w != 0);
    }

    // wave64 reduce
    for (int off = 32; off > 0; off >>= 1) {
        s0 += __shfl_down(s0, off, 64);
        s1 += __shfl_down(s1, off, 64);
        c1 += __shfl_down(c1, off, 64);
    }

    __shared__ float sh0[BLOCK / 64];
    __shared__ float sh1[BLOCK / 64];
    __shared__ unsigned int shc[BLOCK / 64];
    __shared__ bool amLast;

    int lane = threadIdx.x & 63;
    int wave = threadIdx.x >> 6;
    if (lane == 0) { sh0[wave] = s0; sh1[wave] = s1; shc[wave] = c1; }
    __syncthreads();

    if (threadIdx.x == 0) {
        float t0 = 0.f, t1 = 0.f;
        unsigned int tc = 0;
        for (int w = 0; w < BLOCK / 64; ++w) { t0 += sh0[w]; t1 += sh1[w]; tc += shc[w]; }
        // publish partials at device scope
        __hip_atomic_store(&ps0[blockIdx.x], t0, __ATOMIC_RELAXED, __HIP_MEMORY_SCOPE_AGENT);
        __hip_atomic_store(&ps1[blockIdx.x], t1, __ATOMIC_RELAXED, __HIP_MEMORY_SCOPE_AGENT);
        __hip_atomic_store(&pc1[blockIdx.x], tc, __ATOMIC_RELAXED, __HIP_MEMORY_SCOPE_AGENT);
        unsigned int prev = __hip_atomic_fetch_add(counter, 1u, __ATOMIC_ACQ_REL,
                                                   __HIP_MEMORY_SCOPE_AGENT);
        amLast = (prev == (unsigned int)(gridDim.x - 1));
    }
    __syncthreads();

    if (amLast) {
        // last block: reduce all partials (agent-scope loads) and finalize
        float f0 = 0.f, f1 = 0.f;
        unsigned int fc = 0;
        for (int i = threadIdx.x; i < NBLOCKS; i += BLOCK) {
            f0 += __hip_atomic_load(&ps0[i], __ATOMIC_RELAXED, __HIP_MEMORY_SCOPE_AGENT);
            f1 += __hip_atomic_load(&ps1[i], __ATOMIC_RELAXED, __HIP_MEMORY_SCOPE_AGENT);
            fc += __hip_atomic_load(&pc1[i], __ATOMIC_RELAXED, __HIP_MEMORY_SCOPE_AGENT);
        }
        for (int off = 32; off > 0; off >>= 1) {
            f0 += __shfl_down(f0, off, 64);
            f1 += __shfl_down(f1, off, 64);
            fc += __shfl_down(fc, off, 64);
        }
        __syncthreads();  // reuse of sh* below
        if (lane == 0) { sh0[wave] = f0; sh1[wave] = f1; shc[wave] = fc; }
        __syncthreads();
        if (threadIdx.x == 0) {
            float t0 = 0.f, t1 = 0.f;
            unsigned int tc = 0;
            for (int w = 0; w < BLOCK / 64; ++w) { t0 += sh0[w]; t1 += sh1[w]; tc += shc[w]; }
            // tail (N % 4) — normally zero iterations
            for (int i = tail_start; i < N; ++i) {
                float a = x[2 * i], b = x[2 * i + 1];
                float m = fmaxf(a, b);
                float lse = m + __logf(__expf(a - m) + __expf(b - m));
                if (tg[i]) { t1 += lse - b; tc++; } else { t0 += lse - a; }
            }
            unsigned int c0 = (unsigned int)N - tc;
            float r = (tc > 0) ? t1 / (float)tc : 0.f;
            float p = (c0 > 0) ? t0 / (float)c0 : 0.f;
            out[0] = p + r;
        }
    }
}

// Fallback (tiny ws): two-kernel atomic design.
__global__ void nll_atomic(const float4* __restrict__ x4,
                           const int4* __restrict__ t4,
                           float* __restrict__ wsf,
                           unsigned int* __restrict__ wsi,
                           int nquads)
{
    int idx = blockIdx.x * blockDim.x + threadIdx.x;
    int stride = gridDim.x * blockDim.x;
    float s0 = 0.f, s1 = 0.f;
    unsigned int c1 = 0;
    for (int i = idx; i < nquads; i += stride) {
        float4 xa = x4[2 * i];
        float4 xb = x4[2 * i + 1];
        int4   t  = t4[i];
        float a, b, m, lse;
        a = xa.x; b = xa.y; m = fmaxf(a, b);
        lse = m + __logf(__expf(a - m) + __expf(b - m));
        s1 += t.x ? (lse - b) : 0.f; s0 += t.x ? 0.f : (lse - a); c1 += (t.x != 0);
        a = xa.z; b = xa.w; m = fmaxf(a, b);
        lse = m + __logf(__expf(a - m) + __expf(b - m));
        s1 += t.y ? (lse - b) : 0.f; s0 += t.y ? 0.f : (lse - a); c1 += (t.y != 0);
        a = xb.x; b = xb.y; m = fmaxf(a, b);
        lse = m + __logf(__expf(a - m) + __expf(b - m));
        s1 += t.z ? (lse - b) : 0.f; s0 += t.z ? 0.f : (lse - a); c1 += (t.z != 0);
        a = xb.z; b = xb.w; m = fmaxf(a, b);
        lse = m + __logf(__expf(a - m) + __expf(b - m));
        s1 += t.w ? (lse - b) : 0.f; s0 += t.w ? 0.f : (lse - a); c1 += (t.w != 0);
    }
    for (int off = 32; off > 0; off >>= 1) {
        s0 += __shfl_down(s0, off, 64);
        s1 += __shfl_down(s1, off, 64);
        c1 += __shfl_down(c1, off, 64);
    }
    __shared__ float sh0[4]; __shared__ float sh1[4]; __shared__ unsigned int shc[4];
    int lane = threadIdx.x & 63; int wave = threadIdx.x >> 6;
    if (lane == 0) { sh0[wave] = s0; sh1[wave] = s1; shc[wave] = c1; }
    __syncthreads();
    if (threadIdx.x == 0) {
        float t0 = 0.f, t1 = 0.f; unsigned int tc = 0;
        for (int w = 0; w < 4; ++w) { t0 += sh0[w]; t1 += sh1[w]; tc += shc[w]; }
        atomicAdd(&wsf[0], t0); atomicAdd(&wsf[1], t1); atomicAdd(&wsi[0], tc);
    }
}

__global__ void nll_atomic_fin(const float* __restrict__ x,
                               const int* __restrict__ tg,
                               const float* __restrict__ wsf,
                               const unsigned int* __restrict__ wsi,
                               float* __restrict__ out,
                               int N, int tail_start)
{
    float s0 = wsf[0], s1 = wsf[1];
    unsigned int c1 = wsi[0];
    for (int i = tail_start; i < N; ++i) {
        float a = x[2 * i], b = x[2 * i + 1];
        float m = fmaxf(a, b);
        float lse = m + __logf(__expf(a - m) + __expf(b - m));
        if (tg[i]) { s1 += lse - b; c1++; } else { s0 += lse - a; }
    }
    unsigned int c0 = (unsigned int)N - c1;
    float r = (c1 > 0) ? s1 / (float)c1 : 0.f;
    float p = (c0 > 0) ? s0 / (float)c0 : 0.f;
    out[0] = p + r;
}

extern "C" void kernel_launch(void* const* d_in, const int* in_sizes, int n_in,
                              void* d_out, int out_size, void* d_ws, size_t ws_size,
                              hipStream_t stream) {
    const float* x = (const float*)d_in[0];
    const int* tg = (const int*)d_in[1];
    int N = in_sizes[1];
    float* out = (float*)d_out;

    int nquads = N / 4;
    int tail_start = nquads * 4;

    // ws layout: [counter(4B) pad to 16][ps0 NBLOCKS][ps1 NBLOCKS][pc1 NBLOCKS]
    size_t need = 16 + (size_t)NBLOCKS * 12;
    if (ws_size >= need) {
        unsigned int* counter = (unsigned int*)d_ws;
        float* ps0 = (float*)((char*)d_ws + 16);
        float* ps1 = ps0 + NBLOCKS;
        unsigned int* pc1 = (unsigned int*)(ps1 + NBLOCKS);

        hipMemsetAsync(counter, 0, 4, stream);  // zero the completion counter
        nll_fused<<<NBLOCKS, BLOCK, 0, stream>>>(
            (const float4*)x, (const int4*)tg, ps0, ps1, pc1, counter,
            x, tg, out, nquads, N, tail_start);
    } else {
        float* wsf = (float*)d_ws;
        unsigned int* wsi = (unsigned int*)((char*)d_ws + 8);
        hipMemsetAsync(d_ws, 0, 16, stream);
        nll_atomic<<<256, BLOCK, 0, stream>>>(
            (const float4*)x, (const int4*)tg, wsf, wsi, nquads);
        nll_atomic_fin<<<1, 1, 0, stream>>>(x, tg, wsf, wsi, out, N, tail_start);
    }
}

// Round 4
// 112.895 us; speedup vs baseline: 1.8001x; 1.8001x over previous
//
#include <hip/hip_runtime.h>

#define BLOCK 256
#define NBLOCKS 2048
#define BLOCK2 256

// Stage 1: grid-stride over quads of samples; per-block partial sums stored
// to distinct workspace slots. NO atomics, NO release/acquire semantics —
// the kernel boundary provides cross-block ordering (R3 showed per-block
// acq_rel agent atomics cost ~90 us in L2 writeback/invalidate serialization).
__global__ __launch_bounds__(BLOCK) void nll_partial(
    const float4* __restrict__ x4,
    const int4* __restrict__ t4,
    float* __restrict__ ps0,          // [NBLOCKS] sum(-logp | class0)
    float* __restrict__ ps1,          // [NBLOCKS] sum(-logp | class1)
    unsigned int* __restrict__ pc1,   // [NBLOCKS] count(class1)
    int nquads)
{
    int idx = blockIdx.x * blockDim.x + threadIdx.x;
    int stride = gridDim.x * blockDim.x;

    float s0 = 0.f, s1 = 0.f;
    unsigned int c1 = 0;

    for (int i = idx; i < nquads; i += stride) {
        float4 xa = x4[2 * i];
        float4 xb = x4[2 * i + 1];
        int4   t  = t4[i];

        float a, b, m, lse;

        a = xa.x; b = xa.y;
        m = fmaxf(a, b);
        lse = m + __logf(__expf(a - m) + __expf(b - m));
        s1 += t.x ? (lse - b) : 0.f;
        s0 += t.x ? 0.f : (lse - a);
        c1 += (t.x != 0);

        a = xa.z; b = xa.w;
        m = fmaxf(a, b);
        lse = m + __logf(__expf(a - m) + __expf(b - m));
        s1 += t.y ? (lse - b) : 0.f;
        s0 += t.y ? 0.f : (lse - a);
        c1 += (t.y != 0);

        a = xb.x; b = xb.y;
        m = fmaxf(a, b);
        lse = m + __logf(__expf(a - m) + __expf(b - m));
        s1 += t.z ? (lse - b) : 0.f;
        s0 += t.z ? 0.f : (lse - a);
        c1 += (t.z != 0);

        a = xb.z; b = xb.w;
        m = fmaxf(a, b);
        lse = m + __logf(__expf(a - m) + __expf(b - m));
        s1 += t.w ? (lse - b) : 0.f;
        s0 += t.w ? 0.f : (lse - a);
        c1 += (t.w != 0);
    }

    // wave64 reduce
    for (int off = 32; off > 0; off >>= 1) {
        s0 += __shfl_down(s0, off, 64);
        s1 += __shfl_down(s1, off, 64);
        c1 += __shfl_down(c1, off, 64);
    }

    __shared__ float sh0[BLOCK / 64];
    __shared__ float sh1[BLOCK / 64];
    __shared__ unsigned int shc[BLOCK / 64];

    int lane = threadIdx.x & 63;
    int wave = threadIdx.x >> 6;
    if (lane == 0) { sh0[wave] = s0; sh1[wave] = s1; shc[wave] = c1; }
    __syncthreads();

    if (threadIdx.x == 0) {
        float t0 = 0.f, t1 = 0.f;
        unsigned int tc = 0;
        for (int w = 0; w < BLOCK / 64; ++w) { t0 += sh0[w]; t1 += sh1[w]; tc += shc[w]; }
        ps0[blockIdx.x] = t0;   // plain store, unique address per block
        ps1[blockIdx.x] = t1;
        pc1[blockIdx.x] = tc;
    }
}

// Stage 2: one block reduces all partials, handles the (normally empty) tail,
// and writes the final scalar.
__global__ __launch_bounds__(BLOCK2) void nll_finalize(
    const float* __restrict__ ps0,
    const float* __restrict__ ps1,
    const unsigned int* __restrict__ pc1,
    const float* __restrict__ x,
    const int* __restrict__ tg,
    float* __restrict__ out,
    int P, int N, int tail_start)
{
    float s0 = 0.f, s1 = 0.f;
    unsigned int c1 = 0;
    for (int i = threadIdx.x; i < P; i += BLOCK2) {
        s0 += ps0[i];
        s1 += ps1[i];
        c1 += pc1[i];
    }

    for (int off = 32; off > 0; off >>= 1) {
        s0 += __shfl_down(s0, off, 64);
        s1 += __shfl_down(s1, off, 64);
        c1 += __shfl_down(c1, off, 64);
    }

    __shared__ float sh0[BLOCK2 / 64];
    __shared__ float sh1[BLOCK2 / 64];
    __shared__ unsigned int shc[BLOCK2 / 64];

    int lane = threadIdx.x & 63;
    int wave = threadIdx.x >> 6;
    if (lane == 0) { sh0[wave] = s0; sh1[wave] = s1; shc[wave] = c1; }
    __syncthreads();

    if (threadIdx.x == 0) {
        float t0 = 0.f, t1 = 0.f;
        unsigned int tc = 0;
        for (int w = 0; w < BLOCK2 / 64; ++w) { t0 += sh0[w]; t1 += sh1[w]; tc += shc[w]; }
        // tail samples (N % 4) — normally zero iterations
        for (int i = tail_start; i < N; ++i) {
            float a = x[2 * i], b = x[2 * i + 1];
            float m = fmaxf(a, b);
            float lse = m + __logf(__expf(a - m) + __expf(b - m));
            if (tg[i]) { t1 += lse - b; tc++; } else { t0 += lse - a; }
        }
        unsigned int c0 = (unsigned int)N - tc;
        float r = (tc > 0) ? t1 / (float)tc : 0.f;
        float p = (c0 > 0) ? t0 / (float)c0 : 0.f;
        out[0] = p + r;
    }
}

// Fallback (tiny ws): atomic design, only used if ws_size < partial arrays.
__global__ void nll_atomic(const float4* __restrict__ x4,
                           const int4* __restrict__ t4,
                           float* __restrict__ wsf,
                           unsigned int* __restrict__ wsi,
                           int nquads)
{
    int idx = blockIdx.x * blockDim.x + threadIdx.x;
    int stride = gridDim.x * blockDim.x;
    float s0 = 0.f, s1 = 0.f;
    unsigned int c1 = 0;
    for (int i = idx; i < nquads; i += stride) {
        float4 xa = x4[2 * i];
        float4 xb = x4[2 * i + 1];
        int4   t  = t4[i];
        float a, b, m, lse;
        a = xa.x; b = xa.y; m = fmaxf(a, b);
        lse = m + __logf(__expf(a - m) + __expf(b - m));
        s1 += t.x ? (lse - b) : 0.f; s0 += t.x ? 0.f : (lse - a); c1 += (t.x != 0);
        a = xa.z; b = xa.w; m = fmaxf(a, b);
        lse = m + __logf(__expf(a - m) + __expf(b - m));
        s1 += t.y ? (lse - b) : 0.f; s0 += t.y ? 0.f : (lse - a); c1 += (t.y != 0);
        a = xb.x; b = xb.y; m = fmaxf(a, b);
        lse = m + __logf(__expf(a - m) + __expf(b - m));
        s1 += t.z ? (lse - b) : 0.f; s0 += t.z ? 0.f : (lse - a); c1 += (t.z != 0);
        a = xb.z; b = xb.w; m = fmaxf(a, b);
        lse = m + __logf(__expf(a - m) + __expf(b - m));
        s1 += t.w ? (lse - b) : 0.f; s0 += t.w ? 0.f : (lse - a); c1 += (t.w != 0);
    }
    for (int off = 32; off > 0; off >>= 1) {
        s0 += __shfl_down(s0, off, 64);
        s1 += __shfl_down(s1, off, 64);
        c1 += __shfl_down(c1, off, 64);
    }
    __shared__ float sh0[4]; __shared__ float sh1[4]; __shared__ unsigned int shc[4];
    int lane = threadIdx.x & 63; int wave = threadIdx.x >> 6;
    if (lane == 0) { sh0[wave] = s0; sh1[wave] = s1; shc[wave] = c1; }
    __syncthreads();
    if (threadIdx.x == 0) {
        float t0 = 0.f, t1 = 0.f; unsigned int tc = 0;
        for (int w = 0; w < 4; ++w) { t0 += sh0[w]; t1 += sh1[w]; tc += shc[w]; }
        atomicAdd(&wsf[0], t0); atomicAdd(&wsf[1], t1); atomicAdd(&wsi[0], tc);
    }
}

__global__ void nll_atomic_fin(const float* __restrict__ x,
                               const int* __restrict__ tg,
                               const float* __restrict__ wsf,
                               const unsigned int* __restrict__ wsi,
                               float* __restrict__ out,
                               int N, int tail_start)
{
    float s0 = wsf[0], s1 = wsf[1];
    unsigned int c1 = wsi[0];
    for (int i = tail_start; i < N; ++i) {
        float a = x[2 * i], b = x[2 * i + 1];
        float m = fmaxf(a, b);
        float lse = m + __logf(__expf(a - m) + __expf(b - m));
        if (tg[i]) { s1 += lse - b; c1++; } else { s0 += lse - a; }
    }
    unsigned int c0 = (unsigned int)N - c1;
    float r = (c1 > 0) ? s1 / (float)c1 : 0.f;
    float p = (c0 > 0) ? s0 / (float)c0 : 0.f;
    out[0] = p + r;
}

extern "C" void kernel_launch(void* const* d_in, const int* in_sizes, int n_in,
                              void* d_out, int out_size, void* d_ws, size_t ws_size,
                              hipStream_t stream) {
    const float* x = (const float*)d_in[0];
    const int* tg = (const int*)d_in[1];
    int N = in_sizes[1];
    float* out = (float*)d_out;

    int nquads = N / 4;
    int tail_start = nquads * 4;

    size_t need = (size_t)NBLOCKS * (4 + 4 + 4);  // ps0, ps1, pc1
    if (ws_size >= need) {
        float* ps0 = (float*)d_ws;
        float* ps1 = ps0 + NBLOCKS;
        unsigned int* pc1 = (unsigned int*)(ps1 + NBLOCKS);

        nll_partial<<<NBLOCKS, BLOCK, 0, stream>>>(
            (const float4*)x, (const int4*)tg, ps0, ps1, pc1, nquads);
        nll_finalize<<<1, BLOCK2, 0, stream>>>(
            ps0, ps1, pc1, x, tg, out, NBLOCKS, N, tail_start);
    } else {
        float* wsf = (float*)d_ws;
        unsigned int* wsi = (unsigned int*)((char*)d_ws + 8);
        hipMemsetAsync(d_ws, 0, 16, stream);
        nll_atomic<<<256, BLOCK, 0, stream>>>(
            (const float4*)x, (const int4*)tg, wsf, wsi, nquads);
        nll_atomic_fin<<<1, 1, 0, stream>>>(x, tg, wsf, wsi, out, N, tail_start);
    }
}